// Round 1
// baseline (230.373 us; speedup 1.0000x reference)
//
#include <hip/hip_runtime.h>
#include <stdint.h>

// Problem constants (from reference): grid (1, C=12, D=160, H=160, W=160), N=2e6 points.
#define CC 12
#define DD 160
#define HH 160
#define WW 160

static constexpr int    HWi      = HH * WW;                     // 25600
static constexpr int    DHWi     = DD * HH * WW;                // 4,096,000
static constexpr size_t GT_BYTES = (size_t)DHWi * CC * 2;       // 98,304,000 B (bf16 DHWC)

// ---- bf16 helpers (RNE), no dependence on hip_bf16 helpers ----
__device__ __forceinline__ uint32_t pack_bf16(float a, float b) {
    uint32_t ua = __float_as_uint(a);
    uint32_t ub = __float_as_uint(b);
    uint32_t ra = (ua + 0x7fffu + ((ua >> 16) & 1u)) >> 16;
    uint32_t rb = (ub + 0x7fffu + ((ub >> 16) & 1u)) >> 16;
    return (ra & 0xffffu) | (rb << 16);
}
__device__ __forceinline__ float bf_lo(uint32_t q) { return __uint_as_float(q << 16); }
__device__ __forceinline__ float bf_hi(uint32_t q) { return __uint_as_float(q & 0xffff0000u); }

// ---- Pass 1: (C,D,H,W) fp32  ->  (D,H,W,C) bf16 packed into dwords ----
// One thread per (d,h,w). Reads: 12 perfectly coalesced streams (w = lane).
// Writes: 24 B contiguous per thread -> 1536 B contiguous per wave.
__global__ __launch_bounds__(256) void transpose_to_bf16(
    const float* __restrict__ g, uint32_t* __restrict__ gt) {
    int idx = blockIdx.x * 256 + threadIdx.x;
    if (idx >= DHWi) return;
    uint32_t q[6];
#pragma unroll
    for (int j = 0; j < 6; ++j) {
        float a = g[(size_t)(2 * j) * DHWi + idx];
        float b = g[(size_t)(2 * j + 1) * DHWi + idx];
        q[j] = pack_bf16(a, b);   // dword j holds channels 2j (lo), 2j+1 (hi)
    }
    uint2* o = (uint2*)(gt + (size_t)idx * 6);   // byte offset idx*24, 8B-aligned
    o[0] = make_uint2(q[0], q[1]);
    o[1] = make_uint2(q[2], q[3]);
    o[2] = make_uint2(q[4], q[5]);
}

// ---- Pass 2: gather + trilinear interp from (D,H,W,C) bf16 ----
// Per point: 4 contiguous 48-B segments (both w corners x 12 channels).
__global__ __launch_bounds__(256) void trilerp_bf16(
    const float* __restrict__ xyz, const uint32_t* __restrict__ gt,
    const float* __restrict__ xyz_min, const float* __restrict__ xyz_max,
    float* __restrict__ out, int n) {
    int i = blockIdx.x * 256 + threadIdx.x;
    if (i >= n) return;

    float px = xyz[3 * (size_t)i + 0];
    float py = xyz[3 * (size_t)i + 1];
    float pz = xyz[3 * (size_t)i + 2];
    float mn0 = xyz_min[0], mn1 = xyz_min[1], mn2 = xyz_min[2];
    float mx0 = xyz_max[0], mx1 = xyz_max[1], mx2 = xyz_max[2];

    // u = (p - min)/(max - min) * (size-1), clip to [0, size-1]
    float ud = (px - mn0) / (mx0 - mn0) * 159.0f;
    float uh = (py - mn1) / (mx1 - mn1) * 159.0f;
    float uw = (pz - mn2) / (mx2 - mn2) * 159.0f;
    ud = fminf(fmaxf(ud, 0.0f), 159.0f);
    uh = fminf(fmaxf(uh, 0.0f), 159.0f);
    uw = fminf(fmaxf(uw, 0.0f), 159.0f);
    float d0f = fminf(floorf(ud), 158.0f);
    float h0f = fminf(floorf(uh), 158.0f);
    float w0f = fminf(floorf(uw), 158.0f);
    float fd = ud - d0f, fh = uh - h0f, fw = uw - w0f;
    int d0 = (int)d0f, h0 = (int)h0f, w0 = (int)w0f;

    const uint32_t* base = gt + ((size_t)(d0 * HH + h0) * WW + w0) * 6;
    const int sD = HWi * 6;   // d-stride in dwords
    const int sH = WW * 6;    // h-stride in dwords

    float acc[12];
#pragma unroll
    for (int c = 0; c < 12; ++c) acc[c] = 0.0f;

    float wd[2] = {1.0f - fd, fd};
    float wh[2] = {1.0f - fh, fh};

#pragma unroll
    for (int dd = 0; dd < 2; ++dd) {
#pragma unroll
        for (int hh = 0; hh < 2; ++hh) {
            const uint2* p2 = (const uint2*)(base + dd * sD + hh * sH); // 24B-aligned
            uint2 a0 = p2[0], a1 = p2[1], a2 = p2[2];   // w0: channels 0..11
            uint2 b0 = p2[3], b1 = p2[4], b2 = p2[5];   // w1: channels 0..11
            float wdh = wd[dd] * wh[hh];
            uint32_t qa[6] = {a0.x, a0.y, a1.x, a1.y, a2.x, a2.y};
            uint32_t qb[6] = {b0.x, b0.y, b1.x, b1.y, b2.x, b2.y};
#pragma unroll
            for (int j = 0; j < 6; ++j) {
                float v0l = bf_lo(qa[j]), v0h = bf_hi(qa[j]);
                float v1l = bf_lo(qb[j]), v1h = bf_hi(qb[j]);
                float tl = fmaf(fw, v1l - v0l, v0l);    // lerp along w
                float th = fmaf(fw, v1h - v0h, v0h);
                acc[2 * j]     = fmaf(wdh, tl, acc[2 * j]);
                acc[2 * j + 1] = fmaf(wdh, th, acc[2 * j + 1]);
            }
        }
    }

    float4* o = (float4*)(out + (size_t)i * 12);  // byte offset i*48, 16B-aligned
    o[0] = make_float4(acc[0], acc[1], acc[2], acc[3]);
    o[1] = make_float4(acc[4], acc[5], acc[6], acc[7]);
    o[2] = make_float4(acc[8], acc[9], acc[10], acc[11]);
}

// ---- Fallback: direct fp32 gather from native (C,D,H,W) layout ----
__global__ __launch_bounds__(256) void trilerp_direct(
    const float* __restrict__ xyz, const float* __restrict__ g,
    const float* __restrict__ xyz_min, const float* __restrict__ xyz_max,
    float* __restrict__ out, int n) {
    int i = blockIdx.x * 256 + threadIdx.x;
    if (i >= n) return;

    float px = xyz[3 * (size_t)i + 0];
    float py = xyz[3 * (size_t)i + 1];
    float pz = xyz[3 * (size_t)i + 2];
    float mn0 = xyz_min[0], mn1 = xyz_min[1], mn2 = xyz_min[2];
    float mx0 = xyz_max[0], mx1 = xyz_max[1], mx2 = xyz_max[2];

    float ud = (px - mn0) / (mx0 - mn0) * 159.0f;
    float uh = (py - mn1) / (mx1 - mn1) * 159.0f;
    float uw = (pz - mn2) / (mx2 - mn2) * 159.0f;
    ud = fminf(fmaxf(ud, 0.0f), 159.0f);
    uh = fminf(fmaxf(uh, 0.0f), 159.0f);
    uw = fminf(fmaxf(uw, 0.0f), 159.0f);
    float d0f = fminf(floorf(ud), 158.0f);
    float h0f = fminf(floorf(uh), 158.0f);
    float w0f = fminf(floorf(uw), 158.0f);
    float fd = ud - d0f, fh = uh - h0f, fw = uw - w0f;
    int d0 = (int)d0f, h0 = (int)h0f, w0 = (int)w0f;

    size_t base = (size_t)(d0 * HH + h0) * WW + w0;
    float w00 = (1.0f - fd) * (1.0f - fh);
    float w01 = (1.0f - fd) * fh;
    float w10 = fd * (1.0f - fh);
    float w11 = fd * fh;

#pragma unroll
    for (int c = 0; c < CC; ++c) {
        const float* gc = g + (size_t)c * DHWi + base;
        float v000 = gc[0],         v001 = gc[1];
        float v010 = gc[WW],        v011 = gc[WW + 1];
        float v100 = gc[HWi],       v101 = gc[HWi + 1];
        float v110 = gc[HWi + WW],  v111 = gc[HWi + WW + 1];
        float t00 = fmaf(fw, v001 - v000, v000);
        float t01 = fmaf(fw, v011 - v010, v010);
        float t10 = fmaf(fw, v101 - v100, v100);
        float t11 = fmaf(fw, v111 - v110, v110);
        out[(size_t)i * CC + c] = w00 * t00 + w01 * t01 + w10 * t10 + w11 * t11;
    }
}

extern "C" void kernel_launch(void* const* d_in, const int* in_sizes, int n_in,
                              void* d_out, int out_size, void* d_ws, size_t ws_size,
                              hipStream_t stream) {
    const float* xyz  = (const float*)d_in[0];
    const float* grid = (const float*)d_in[1];
    const float* mn   = (const float*)d_in[2];
    const float* mx   = (const float*)d_in[3];
    float* out = (float*)d_out;
    int n = in_sizes[0] / 3;

    if (ws_size >= GT_BYTES) {
        uint32_t* gt = (uint32_t*)d_ws;
        transpose_to_bf16<<<DHWi / 256, 256, 0, stream>>>(grid, gt);
        trilerp_bf16<<<(n + 255) / 256, 256, 0, stream>>>(xyz, gt, mn, mx, out, n);
    } else {
        trilerp_direct<<<(n + 255) / 256, 256, 0, stream>>>(xyz, grid, mn, mx, out, n);
    }
}